// Round 1
// baseline (66.373 us; speedup 1.0000x reference)
//
#include <hip/hip_runtime.h>

#define NPOS 8192
#define NNEG 40960
#define NEDGE (NPOS + NNEG)
#define DIM 128
#define MARGIN 0.1f

// -------- kernel 1: one wave (64 lanes) per edge, dot product of two rows ----
__global__ __launch_bounds__(256) void sims_kernel(
    const float* __restrict__ emb,
    const int* __restrict__ pos_idx,
    const int* __restrict__ neg_idx,
    float* __restrict__ sims, float* __restrict__ acc) {
  if (blockIdx.x == 0 && threadIdx.x == 0) acc[0] = 0.f;  // zero accumulator for kernel 2
  int gtid = blockIdx.x * 256 + threadIdx.x;
  int wave = gtid >> 6;
  int lane = threadIdx.x & 63;
  if (wave >= NEDGE) return;
  int s, d;
  if (wave < NPOS) {
    s = pos_idx[wave];
    d = pos_idx[NPOS + wave];
  } else {
    int e = wave - NPOS;
    s = neg_idx[e];
    d = neg_idx[NNEG + e];
  }
  const float2 a = *(const float2*)(emb + (long long)s * DIM + lane * 2);
  const float2 b = *(const float2*)(emb + (long long)d * DIM + lane * 2);
  float v = a.x * b.x + a.y * b.y;
#pragma unroll
  for (int m = 32; m >= 1; m >>= 1) v += __shfl_xor(v, m, 64);
  if (lane == 0) sims[wave] = v;
}

// -------- kernel 2: A = sum_{i,j} |n_j - (p_i - MARGIN)|  --------------------
// grid = 8 pos-chunks (1024 each) x 80 neg-segments (512 each) = 640 blocks
#define POSC 1024
#define NEGSEG 512

__global__ __launch_bounds__(256) void pair_kernel(
    const float* __restrict__ sims, float* __restrict__ acc) {
  __shared__ float sneg[NEGSEG];
  const float* pos = sims;
  const float* neg = sims + NPOS;
  const int pc = blockIdx.x & 7;   // pos chunk
  const int ns = blockIdx.x >> 3;  // neg segment
  const int tid = threadIdx.x;

  for (int t = tid; t < NEGSEG; t += 256) sneg[t] = neg[ns * NEGSEG + t];

  const int pb = pc * POSC + tid;
  const float q0 = pos[pb]       - MARGIN;
  const float q1 = pos[pb + 256] - MARGIN;
  const float q2 = pos[pb + 512] - MARGIN;
  const float q3 = pos[pb + 768] - MARGIN;
  __syncthreads();

  float a0 = 0.f, a1 = 0.f, a2 = 0.f, a3 = 0.f;
#pragma unroll 4
  for (int j = 0; j < NEGSEG; j += 4) {
    const float4 n = *(const float4*)(sneg + j);
    a0 += fabsf(n.x - q0); a1 += fabsf(n.x - q1);
    a2 += fabsf(n.x - q2); a3 += fabsf(n.x - q3);
    a0 += fabsf(n.y - q0); a1 += fabsf(n.y - q1);
    a2 += fabsf(n.y - q2); a3 += fabsf(n.y - q3);
    a0 += fabsf(n.z - q0); a1 += fabsf(n.z - q1);
    a2 += fabsf(n.z - q2); a3 += fabsf(n.z - q3);
    a0 += fabsf(n.w - q0); a1 += fabsf(n.w - q1);
    a2 += fabsf(n.w - q2); a3 += fabsf(n.w - q3);
  }

  float a = (a0 + a1) + (a2 + a3);
#pragma unroll
  for (int m = 32; m >= 1; m >>= 1) a += __shfl_xor(a, m, 64);
  __shared__ float wsum[4];
  if ((tid & 63) == 0) wsum[tid >> 6] = a;
  __syncthreads();
  if (tid == 0) atomicAdd(acc, (wsum[0] + wsum[1]) + (wsum[2] + wsum[3]));
}

// -------- kernel 3: closed-form S + final combine -----------------------------
__global__ __launch_bounds__(256) void finalize_kernel(
    const float* __restrict__ sims, const float* __restrict__ acc,
    float* __restrict__ out) {
  const int tid = threadIdx.x;
  float sp = 0.f, sn = 0.f;
  for (int i = tid; i < NPOS; i += 256) sp += sims[i];
  for (int j = tid; j < NNEG; j += 256) sn += sims[NPOS + j];
#pragma unroll
  for (int m = 32; m >= 1; m >>= 1) {
    sp += __shfl_xor(sp, m, 64);
    sn += __shfl_xor(sn, m, 64);
  }
  __shared__ float wp[4], wn[4];
  if ((tid & 63) == 0) { wp[tid >> 6] = sp; wn[tid >> 6] = sn; }
  __syncthreads();
  if (tid == 0) {
    double Sp = (double)((wp[0] + wp[1]) + (wp[2] + wp[3]));
    double Sn = (double)((wn[0] + wn[1]) + (wn[2] + wn[3]));
    // S = sum_{i,j} (MARGIN - p_i + n_j)
    double S = (double)NNEG * ((double)NPOS * (double)MARGIN - Sp) +
               (double)NPOS * Sn;
    double A = (double)acc[0];
    double loss = 0.5 * (S + A) / ((double)NPOS * (double)NNEG);
    out[0] = (float)loss;  // LAMBDA_STRUCT = 1.0
  }
}

extern "C" void kernel_launch(void* const* d_in, const int* in_sizes, int n_in,
                              void* d_out, int out_size, void* d_ws, size_t ws_size,
                              hipStream_t stream) {
  const float* emb = (const float*)d_in[0];
  const int* pos_idx = (const int*)d_in[1];
  const int* neg_idx = (const int*)d_in[2];
  float* out = (float*)d_out;

  float* wsf = (float*)d_ws;
  float* acc = wsf;        // 1 float accumulator
  float* sims = wsf + 64;  // 49152 floats of sims (pos then neg)

  // kernel 1: 49152 edges, one wave each, 4 waves/block
  sims_kernel<<<NEDGE / 4, 256, 0, stream>>>(emb, pos_idx, neg_idx, sims, acc);

  // kernel 2: 8 pos-chunks x 80 neg-segments
  pair_kernel<<<(NPOS / POSC) * (NNEG / NEGSEG), 256, 0, stream>>>(sims, acc);

  // kernel 3
  finalize_kernel<<<1, 256, 0, stream>>>(sims, acc, out);
}